// Round 1
// baseline (199.719 us; speedup 1.0000x reference)
//
#include <hip/hip_runtime.h>

#define N_GAUSS 1024
#define H_DIM 768
#define W_DIM 768

// Per-gaussian packed params in workspace: {mx, my, A, Bc, D, wr, wg, wb}
// exponent for exp2: A*dx^2 + Bc*dx*dy + D*dy^2  (the -0.5*log2(e) factor is
// folded into A/Bc/D so the hot loop is a single v_exp_f32 per pixel).

__global__ __launch_bounds__(256) void prep_kernel(
    const float* __restrict__ means, const float* __restrict__ covs,
    const float* __restrict__ colors, float* __restrict__ gp) {
  int n = blockIdx.x * 256 + threadIdx.x;
  if (n >= N_GAUSS) return;
  float mx = means[n * 2 + 0];
  float my = means[n * 2 + 1];
  float a = covs[n * 4 + 0];
  float b = covs[n * 4 + 1];
  float c = covs[n * 4 + 2];
  float d = covs[n * 4 + 3];
  float inv = 1.0f / (a * d - b * c);
  const float L = -0.72134752044448170368f;  // -0.5 * log2(e)
  float A  = L * d * inv;          // L * ia
  float Bc = -L * (b + c) * inv;   // L * (ib + ic)
  float D  = L * a * inv;          // L * id
  float cr = colors[n * 4 + 0];
  float cg = colors[n * 4 + 1];
  float cb = colors[n * 4 + 2];
  float al = colors[n * 4 + 3];
  // weighted rgb = sigmoid(c) * alpha  (alpha NOT sigmoided)
  float wr = al / (1.0f + expf(-cr));
  float wg = al / (1.0f + expf(-cg));
  float wb = al / (1.0f + expf(-cb));
  float* g = gp + n * 8;
  g[0] = mx; g[1] = my; g[2] = A; g[3] = Bc; g[4] = D;
  g[5] = wr; g[6] = wg; g[7] = wb;
}

// One block per row h. All per-gaussian derived values (dx, qa, qb) are
// wave-uniform -> scalar loads + SALU, overlapping the VALU pixel work.
// Each thread owns 3 pixels: (h, t), (h, t+256), (h, t+512).
__global__ __launch_bounds__(256) void render_kernel(
    const float* __restrict__ gp, float* __restrict__ out) {
  const int h = blockIdx.x;
  const int t = threadIdx.x;
  const float scale = 1.0f / 767.0f;  // linspace(0,1,768) step
  const float x  = (float)h * scale;
  const float y0 = (float)t * scale;
  const float y1 = (float)(t + 256) * scale;
  const float y2 = (float)(t + 512) * scale;

  float r0 = 0.f, g0 = 0.f, b0 = 0.f;
  float r1 = 0.f, g1 = 0.f, b1 = 0.f;
  float r2 = 0.f, g2 = 0.f, b2 = 0.f;

#pragma unroll 4
  for (int n = 0; n < N_GAUSS; ++n) {
    const float* g = gp + n * 8;
    const float mx = g[0], my = g[1], A = g[2], Bc = g[3], D = g[4];
    const float wr = g[5], wg = g[6], wb = g[7];
    // wave-uniform (h fixed per block) -> SALU
    const float dx = x - mx;
    const float qa = A * dx * dx;
    const float qb = Bc * dx;

    float dy = y0 - my;
    float v = __builtin_amdgcn_exp2f(fmaf(fmaf(D, dy, qb), dy, qa));
    r0 = fmaf(v, wr, r0); g0 = fmaf(v, wg, g0); b0 = fmaf(v, wb, b0);

    dy = y1 - my;
    v = __builtin_amdgcn_exp2f(fmaf(fmaf(D, dy, qb), dy, qa));
    r1 = fmaf(v, wr, r1); g1 = fmaf(v, wg, g1); b1 = fmaf(v, wb, b1);

    dy = y2 - my;
    v = __builtin_amdgcn_exp2f(fmaf(fmaf(D, dy, qb), dy, qa));
    r2 = fmaf(v, wr, r2); g2 = fmaf(v, wg, g2); b2 = fmaf(v, wb, b2);
  }

  float* o = out + ((size_t)h * W_DIM + t) * 3;
  o[0] = r0; o[1] = g0; o[2] = b0;
  o = out + ((size_t)h * W_DIM + t + 256) * 3;
  o[0] = r1; o[1] = g1; o[2] = b1;
  o = out + ((size_t)h * W_DIM + t + 512) * 3;
  o[0] = r2; o[1] = g2; o[2] = b2;
}

extern "C" void kernel_launch(void* const* d_in, const int* in_sizes, int n_in,
                              void* d_out, int out_size, void* d_ws, size_t ws_size,
                              hipStream_t stream) {
  const float* means  = (const float*)d_in[0];   // (N,2,1)
  const float* covs   = (const float*)d_in[1];   // (N,2,2)
  const float* colors = (const float*)d_in[2];   // (N,4)
  float* gp = (float*)d_ws;                      // N*8 floats = 32 KB
  float* out = (float*)d_out;                    // (768,768,3) fp32

  prep_kernel<<<dim3(N_GAUSS / 256), dim3(256), 0, stream>>>(means, covs, colors, gp);
  render_kernel<<<dim3(H_DIM), dim3(256), 0, stream>>>(gp, out);
}